// Round 2
// baseline (865.998 us; speedup 1.0000x reference)
//
#include <hip/hip_runtime.h>
#include <hip/hip_fp16.h>

#define NCH 64
#define EPS 1e-5f
#define NPASS 8

// ---------------- degree / dinv ----------------
__global__ void k_deg(const int* __restrict__ dst, int* __restrict__ deg, int E) {
    int e = blockIdx.x * blockDim.x + threadIdx.x;
    if (e < E) atomicAdd(&deg[dst[e]], 1);
}

__global__ void k_dinv(const int* __restrict__ deg, float* __restrict__ dinv, int N) {
    int i = blockIdx.x * blockDim.x + threadIdx.x;
    if (i < N) {
        int d = deg[i];
        dinv[i] = (d > 0) ? rsqrtf((float)d) : 0.0f;
    }
}

// ---------------- fp32 -> fp16 cast ----------------
__global__ void k_cast(const float* __restrict__ x, __half* __restrict__ xh, int total) {
    int i = blockIdx.x * blockDim.x + threadIdx.x;
    if (i < total) xh[i] = __float2half(x[i]);
}

// ---------------- 3-kernel exclusive scan of deg -> rowstart ----------------
__global__ void k_scan1(const int* __restrict__ deg, int* __restrict__ bsum, int N) {
    __shared__ int s[256];
    int t = threadIdx.x;
    int i = blockIdx.x * 256 + t;
    s[t] = (i < N) ? deg[i] : 0;
    __syncthreads();
    for (int off = 128; off > 0; off >>= 1) {
        if (t < off) s[t] += s[t + off];
        __syncthreads();
    }
    if (t == 0) bsum[blockIdx.x] = s[0];
}

__global__ void k_scan2(int* __restrict__ bsum, int NB) {
    __shared__ int s[512];
    int t = threadIdx.x;
    int v = (t < NB) ? bsum[t] : 0;
    s[t] = v;
    __syncthreads();
    for (int off = 1; off < 512; off <<= 1) {
        int add = (t >= off) ? s[t - off] : 0;
        __syncthreads();
        s[t] += add;
        __syncthreads();
    }
    if (t < NB) bsum[t] = s[t] - v;  // exclusive
}

__global__ void k_scan3(const int* __restrict__ deg, const int* __restrict__ bsum,
                        int* __restrict__ rowstart, int N, int E) {
    __shared__ int s[256];
    int t = threadIdx.x;
    int i = blockIdx.x * 256 + t;
    int v = (i < N) ? deg[i] : 0;
    s[t] = v;
    __syncthreads();
    for (int off = 1; off < 256; off <<= 1) {
        int add = (t >= off) ? s[t - off] : 0;
        __syncthreads();
        s[t] += add;
        __syncthreads();
    }
    if (i < N) rowstart[i] = bsum[blockIdx.x] + (s[t] - v);
    if (i == N - 1) rowstart[N] = E;
}

// ---------------- CSR fill, multi-pass by dst range for write locality ----------------
// Pass p only handles dst in [p*npp, (p+1)*npp): write region 12.8MB/NPASS = 1.6MB
// -> L2-resident, scattered 8B writes combine before eviction. Passes are disjoint
// work, no barrier needed; blocks drift but locality is heuristic.
__global__ __launch_bounds__(256) void k_fill_mp(const int* __restrict__ src,
                                                 const int* __restrict__ dst,
                                                 const float* __restrict__ dinv,
                                                 const int* __restrict__ rowstart,
                                                 int* __restrict__ cursor,
                                                 int2* __restrict__ csr, int E, int npp) {
    int stride = gridDim.x * blockDim.x;
    int t0 = blockIdx.x * blockDim.x + threadIdx.x;
    for (int p = 0; p < NPASS; p++) {
        int lo = p * npp, hi = lo + npp;
        for (int e = t0; e < E; e += stride) {
            int d = dst[e];
            if (d < lo || d >= hi) continue;
            int s = src[e];
            float w = -dinv[s] * dinv[d];
            int pos = atomicAdd(&cursor[d], 1);
            csr[rowstart[d] + pos] = make_int2(s, __float_as_int(w));
        }
    }
}

// ---------------- propagation: y = prop(h)  (or 2*prop(h) - tx0), fp16 storage ----------------
// one wave per dst node, lane = channel; fp32 accumulate
__global__ __launch_bounds__(256) void k_prop(const __half* __restrict__ h,
                                              const int* __restrict__ rowstart,
                                              const int2* __restrict__ csr,
                                              const __half* __restrict__ tx0,
                                              __half* __restrict__ y, int N) {
    int gid = blockIdx.x * blockDim.x + threadIdx.x;
    int node = gid >> 6;
    int lane = gid & 63;
    if (node >= N) return;
    int e = rowstart[node];
    int s1 = rowstart[node + 1];
    float acc = 0.0f;
    for (; e + 4 <= s1; e += 4) {
        int2 c0 = csr[e], c1 = csr[e + 1], c2 = csr[e + 2], c3 = csr[e + 3];
        float h0 = __half2float(h[c0.x * NCH + lane]);
        float h1 = __half2float(h[c1.x * NCH + lane]);
        float h2 = __half2float(h[c2.x * NCH + lane]);
        float h3 = __half2float(h[c3.x * NCH + lane]);
        acc = fmaf(__int_as_float(c0.y), h0, acc);
        acc = fmaf(__int_as_float(c1.y), h1, acc);
        acc = fmaf(__int_as_float(c2.y), h2, acc);
        acc = fmaf(__int_as_float(c3.y), h3, acc);
    }
    for (; e < s1; e++) {
        int2 c = csr[e];
        acc = fmaf(__int_as_float(c.y), __half2float(h[c.x * NCH + lane]), acc);
    }
    float r = acc;
    if (tx0 != nullptr) r = 2.0f * acc - __half2float(tx0[node * NCH + lane]);
    y[node * NCH + lane] = __float2half(r);
}

// ---------------- dense combine + ReLU + fused instance-norm stats ----------------
// one wave per 4 nodes; lane = output channel; W flattened [192][64]
template <typename TOUT>
__global__ __launch_bounds__(256) void k_dense(const __half* __restrict__ tx0,
                                               const __half* __restrict__ tx1,
                                               const __half* __restrict__ tx2,
                                               const float* __restrict__ W,
                                               const float* __restrict__ b,
                                               TOUT* __restrict__ out,
                                               float* __restrict__ stats, int N) {
    __shared__ float sh[4][4][192];
    __shared__ float red[4][128];
    int t = threadIdx.x;
    int w = t >> 6;
    int lane = t & 63;
    int nodeBase = blockIdx.x * 16 + w * 4;
    for (int n = 0; n < 4; n++) {
        int node = nodeBase + n;
        if (node < N) {
            sh[w][n][lane]       = __half2float(tx0[node * NCH + lane]);
            sh[w][n][64 + lane]  = __half2float(tx1[node * NCH + lane]);
            sh[w][n][128 + lane] = __half2float(tx2[node * NCH + lane]);
        } else {
            sh[w][n][lane] = 0.0f;
            sh[w][n][64 + lane] = 0.0f;
            sh[w][n][128 + lane] = 0.0f;
        }
    }
    __syncthreads();
    float bb = b[lane];
    float acc0 = bb, acc1 = bb, acc2 = bb, acc3 = bb;
#pragma unroll 4
    for (int j = 0; j < 192; j += 4) {
        float4 t0 = *(const float4*)&sh[w][0][j];
        float4 t1 = *(const float4*)&sh[w][1][j];
        float4 t2 = *(const float4*)&sh[w][2][j];
        float4 t3 = *(const float4*)&sh[w][3][j];
        float w0 = W[(j + 0) * NCH + lane];
        float w1 = W[(j + 1) * NCH + lane];
        float w2 = W[(j + 2) * NCH + lane];
        float w3 = W[(j + 3) * NCH + lane];
        acc0 = fmaf(t0.x, w0, acc0); acc0 = fmaf(t0.y, w1, acc0);
        acc0 = fmaf(t0.z, w2, acc0); acc0 = fmaf(t0.w, w3, acc0);
        acc1 = fmaf(t1.x, w0, acc1); acc1 = fmaf(t1.y, w1, acc1);
        acc1 = fmaf(t1.z, w2, acc1); acc1 = fmaf(t1.w, w3, acc1);
        acc2 = fmaf(t2.x, w0, acc2); acc2 = fmaf(t2.y, w1, acc2);
        acc2 = fmaf(t2.z, w2, acc2); acc2 = fmaf(t2.w, w3, acc2);
        acc3 = fmaf(t3.x, w0, acc3); acc3 = fmaf(t3.y, w1, acc3);
        acc3 = fmaf(t3.z, w2, acc3); acc3 = fmaf(t3.w, w3, acc3);
    }
    acc0 = fmaxf(acc0, 0.0f);
    acc1 = fmaxf(acc1, 0.0f);
    acc2 = fmaxf(acc2, 0.0f);
    acc3 = fmaxf(acc3, 0.0f);
    bool v0 = nodeBase + 0 < N, v1 = nodeBase + 1 < N, v2 = nodeBase + 2 < N, v3 = nodeBase + 3 < N;
    if (v0) out[(nodeBase + 0) * NCH + lane] = (TOUT)acc0;
    if (v1) out[(nodeBase + 1) * NCH + lane] = (TOUT)acc1;
    if (v2) out[(nodeBase + 2) * NCH + lane] = (TOUT)acc2;
    if (v3) out[(nodeBase + 3) * NCH + lane] = (TOUT)acc3;
    // fused per-channel stats (mask invalid nodes)
    float s = (v0 ? acc0 : 0.f) + (v1 ? acc1 : 0.f) + (v2 ? acc2 : 0.f) + (v3 ? acc3 : 0.f);
    float q = (v0 ? acc0 * acc0 : 0.f) + (v1 ? acc1 * acc1 : 0.f) +
              (v2 ? acc2 * acc2 : 0.f) + (v3 ? acc3 * acc3 : 0.f);
    red[w][lane] = s;
    red[w][64 + lane] = q;
    __syncthreads();
    if (w == 0) {
        float S = red[0][lane] + red[1][lane] + red[2][lane] + red[3][lane];
        float Q = red[0][64 + lane] + red[1][64 + lane] + red[2][64 + lane] + red[3][64 + lane];
        atomicAdd(&stats[lane], S);
        atomicAdd(&stats[64 + lane], Q);
    }
}

__global__ void k_final(float* __restrict__ stats, float invN) {
    int c = threadIdx.x;
    float m = stats[c] * invN;
    float q = stats[64 + c] * invN;
    float var = q - m * m;
    stats[128 + c] = m;
    stats[192 + c] = rsqrtf(var + EPS);
}

__global__ void k_norm_h(__half* __restrict__ h, const float* __restrict__ stats, int total) {
    int i = blockIdx.x * blockDim.x + threadIdx.x;
    if (i >= total) return;
    int lane = i & 63;
    h[i] = __float2half((__half2float(h[i]) - stats[128 + lane]) * stats[192 + lane]);
}

__global__ void k_norm_f(float* __restrict__ h, const float* __restrict__ stats, int total) {
    int i = blockIdx.x * blockDim.x + threadIdx.x;
    if (i >= total) return;
    int lane = i & 63;
    h[i] = (h[i] - stats[128 + lane]) * stats[192 + lane];
}

// ---------------- launcher ----------------
extern "C" void kernel_launch(void* const* d_in, const int* in_sizes, int n_in,
                              void* d_out, int out_size, void* d_ws, size_t ws_size,
                              hipStream_t stream) {
    const float* x  = (const float*)d_in[0];
    const int*   ei = (const int*)d_in[1];
    const float* W1 = (const float*)d_in[2];
    const float* b1 = (const float*)d_in[3];
    const float* W2 = (const float*)d_in[4];
    const float* b2 = (const float*)d_in[5];
    float* out = (float*)d_out;

    const int N = in_sizes[0] / NCH;
    const int E = in_sizes[1] / 2;
    const int* src = ei;
    const int* dst = ei + E;

    // workspace carve (256B aligned)
    char* p = (char*)d_ws;
    auto alloc = [&](size_t bytes) {
        void* r = (void*)p;
        p += ((bytes + 255) / 256) * 256;
        return r;
    };
    int*    deg      = (int*)alloc((size_t)N * 4);
    float*  dinv     = (float*)alloc((size_t)N * 4);
    int*    rowstart = (int*)alloc((size_t)(N + 1) * 4);
    int*    cursor   = (int*)alloc((size_t)N * 4);
    const int NB1 = (N + 255) / 256;
    int*    bsum     = (int*)alloc((size_t)NB1 * 4);
    int2*   csr      = (int2*)alloc((size_t)E * 8);
    __half* xh       = (__half*)alloc((size_t)N * NCH * 2);
    __half* Tx1      = (__half*)alloc((size_t)N * NCH * 2);
    __half* Tx2      = (__half*)alloc((size_t)N * NCH * 2);
    __half* A        = (__half*)alloc((size_t)N * NCH * 2);
    float*  stats1   = (float*)alloc(256 * 4);
    float*  stats2   = (float*)alloc(256 * 4);

    hipMemsetAsync(deg, 0, (size_t)N * 4, stream);
    hipMemsetAsync(cursor, 0, (size_t)N * 4, stream);
    hipMemsetAsync(stats1, 0, 128 * 4, stream);
    hipMemsetAsync(stats2, 0, 128 * 4, stream);

    const int TB = 256;
    const int npp = (N + NPASS - 1) / NPASS;
    // build CSR (by dst) + edge weights
    k_deg<<<(E + TB - 1) / TB, TB, 0, stream>>>(dst, deg, E);
    k_dinv<<<(N + TB - 1) / TB, TB, 0, stream>>>(deg, dinv, N);
    k_scan1<<<NB1, 256, 0, stream>>>(deg, bsum, N);
    k_scan2<<<1, 512, 0, stream>>>(bsum, NB1);
    k_scan3<<<NB1, 256, 0, stream>>>(deg, bsum, rowstart, N, E);
    k_fill_mp<<<2048, TB, 0, stream>>>(src, dst, dinv, rowstart, cursor, csr, E, npp);
    k_cast<<<(N * NCH + TB - 1) / TB, TB, 0, stream>>>(x, xh, N * NCH);

    const int propBlocks = (N * NCH + TB - 1) / TB;
    const int denseBlocks = (N + 15) / 16;
    const int normBlocks = (N * NCH + TB - 1) / TB;
    const float invN = 1.0f / (float)N;

    // ---- layer 1 ----
    k_prop<<<propBlocks, TB, 0, stream>>>(xh, rowstart, csr, nullptr, Tx1, N);
    k_prop<<<propBlocks, TB, 0, stream>>>(Tx1, rowstart, csr, xh, Tx2, N);
    k_dense<__half><<<denseBlocks, TB, 0, stream>>>(xh, Tx1, Tx2, W1, b1, A, stats1, N);
    k_final<<<1, 64, 0, stream>>>(stats1, invN);
    k_norm_h<<<normBlocks, TB, 0, stream>>>(A, stats1, N * NCH);

    // ---- layer 2 ----
    k_prop<<<propBlocks, TB, 0, stream>>>(A, rowstart, csr, nullptr, Tx1, N);
    k_prop<<<propBlocks, TB, 0, stream>>>(Tx1, rowstart, csr, A, Tx2, N);
    k_dense<float><<<denseBlocks, TB, 0, stream>>>(A, Tx1, Tx2, W2, b2, out, stats2, N);
    k_final<<<1, 64, 0, stream>>>(stats2, invN);
    k_norm_f<<<normBlocks, TB, 0, stream>>>(out, stats2, N * NCH);
}

// Round 3
// 658.124 us; speedup vs baseline: 1.3159x; 1.3159x over previous
//
#include <hip/hip_runtime.h>
#include <hip/hip_fp16.h>

#define NCH 64
#define EPS 1e-5f
#define NPASS 8
#define SBANKS 32   // stats atomic banks: 3125 blocks / 32 ~ 98 atomics per address

// ---------------- degree / dinv ----------------
__global__ void k_deg(const int* __restrict__ dst, int* __restrict__ deg, int E) {
    int e = blockIdx.x * blockDim.x + threadIdx.x;
    if (e < E) atomicAdd(&deg[dst[e]], 1);
}

__global__ void k_dinv(const int* __restrict__ deg, float* __restrict__ dinv, int N) {
    int i = blockIdx.x * blockDim.x + threadIdx.x;
    if (i < N) {
        int d = deg[i];
        dinv[i] = (d > 0) ? rsqrtf((float)d) : 0.0f;
    }
}

// ---------------- fp32 -> fp16 cast ----------------
__global__ void k_cast(const float* __restrict__ x, __half* __restrict__ xh, int total) {
    int i = blockIdx.x * blockDim.x + threadIdx.x;
    if (i < total) xh[i] = __float2half(x[i]);
}

// ---------------- 3-kernel exclusive scan of deg -> rowstart ----------------
__global__ void k_scan1(const int* __restrict__ deg, int* __restrict__ bsum, int N) {
    __shared__ int s[256];
    int t = threadIdx.x;
    int i = blockIdx.x * 256 + t;
    s[t] = (i < N) ? deg[i] : 0;
    __syncthreads();
    for (int off = 128; off > 0; off >>= 1) {
        if (t < off) s[t] += s[t + off];
        __syncthreads();
    }
    if (t == 0) bsum[blockIdx.x] = s[0];
}

__global__ void k_scan2(int* __restrict__ bsum, int NB) {
    __shared__ int s[512];
    int t = threadIdx.x;
    int v = (t < NB) ? bsum[t] : 0;
    s[t] = v;
    __syncthreads();
    for (int off = 1; off < 512; off <<= 1) {
        int add = (t >= off) ? s[t - off] : 0;
        __syncthreads();
        s[t] += add;
        __syncthreads();
    }
    if (t < NB) bsum[t] = s[t] - v;  // exclusive
}

__global__ void k_scan3(const int* __restrict__ deg, const int* __restrict__ bsum,
                        int* __restrict__ rowstart, int N, int E) {
    __shared__ int s[256];
    int t = threadIdx.x;
    int i = blockIdx.x * 256 + t;
    int v = (i < N) ? deg[i] : 0;
    s[t] = v;
    __syncthreads();
    for (int off = 1; off < 256; off <<= 1) {
        int add = (t >= off) ? s[t - off] : 0;
        __syncthreads();
        s[t] += add;
        __syncthreads();
    }
    if (i < N) rowstart[i] = bsum[blockIdx.x] + (s[t] - v);
    if (i == N - 1) rowstart[N] = E;
}

// ---------------- CSR fill, multi-pass by dst range for write locality ----------------
__global__ __launch_bounds__(256) void k_fill_mp(const int* __restrict__ src,
                                                 const int* __restrict__ dst,
                                                 const float* __restrict__ dinv,
                                                 const int* __restrict__ rowstart,
                                                 int* __restrict__ cursor,
                                                 int2* __restrict__ csr, int E, int npp) {
    int stride = gridDim.x * blockDim.x;
    int t0 = blockIdx.x * blockDim.x + threadIdx.x;
    for (int p = 0; p < NPASS; p++) {
        int lo = p * npp, hi = lo + npp;
        for (int e = t0; e < E; e += stride) {
            int d = dst[e];
            if (d < lo || d >= hi) continue;
            int s = src[e];
            float w = -dinv[s] * dinv[d];
            int pos = atomicAdd(&cursor[d], 1);
            csr[rowstart[d] + pos] = make_int2(s, __float_as_int(w));
        }
    }
}

// ---------------- propagation: y = prop(h)  (or 2*prop(h) - tx0), fp16 storage ----------------
__global__ __launch_bounds__(256) void k_prop(const __half* __restrict__ h,
                                              const int* __restrict__ rowstart,
                                              const int2* __restrict__ csr,
                                              const __half* __restrict__ tx0,
                                              __half* __restrict__ y, int N) {
    int gid = blockIdx.x * blockDim.x + threadIdx.x;
    int node = gid >> 6;
    int lane = gid & 63;
    if (node >= N) return;
    int e = rowstart[node];
    int s1 = rowstart[node + 1];
    float acc = 0.0f;
    for (; e + 4 <= s1; e += 4) {
        int2 c0 = csr[e], c1 = csr[e + 1], c2 = csr[e + 2], c3 = csr[e + 3];
        float h0 = __half2float(h[c0.x * NCH + lane]);
        float h1 = __half2float(h[c1.x * NCH + lane]);
        float h2 = __half2float(h[c2.x * NCH + lane]);
        float h3 = __half2float(h[c3.x * NCH + lane]);
        acc = fmaf(__int_as_float(c0.y), h0, acc);
        acc = fmaf(__int_as_float(c1.y), h1, acc);
        acc = fmaf(__int_as_float(c2.y), h2, acc);
        acc = fmaf(__int_as_float(c3.y), h3, acc);
    }
    for (; e < s1; e++) {
        int2 c = csr[e];
        acc = fmaf(__int_as_float(c.y), __half2float(h[c.x * NCH + lane]), acc);
    }
    float r = acc;
    if (tx0 != nullptr) r = 2.0f * acc - __half2float(tx0[node * NCH + lane]);
    y[node * NCH + lane] = __float2half(r);
}

// ---------------- dense combine + ReLU + banked instance-norm stats ----------------
// one wave per 8 nodes (32/block); lane = output channel; W flattened [192][64]
// statsP layout: [SBANKS][128] partials, then [128] for mean/rstd (filled by k_final)
template <typename TOUT>
__global__ __launch_bounds__(256) void k_dense(const __half* __restrict__ tx0,
                                               const __half* __restrict__ tx1,
                                               const __half* __restrict__ tx2,
                                               const float* __restrict__ W,
                                               const float* __restrict__ b,
                                               TOUT* __restrict__ out,
                                               float* __restrict__ statsP, int N) {
    __shared__ float sh[4][8][192];   // 24576 B
    __shared__ float red[4][128];     //  2048 B
    int t = threadIdx.x;
    int w = t >> 6;
    int lane = t & 63;
    int nodeBase = blockIdx.x * 32 + w * 8;

    // vectorized stage: each wave's 8 node-rows are contiguous (512 halves per tensor)
    const __half* p0 = tx0 + (size_t)nodeBase * NCH;
    const __half* p1 = tx1 + (size_t)nodeBase * NCH;
    const __half* p2 = tx2 + (size_t)nodeBase * NCH;
#pragma unroll
    for (int v = 0; v < 2; v++) {
        int i = v * 256 + lane * 4;       // half index within the 8x64 slice
        int n = i >> 6, c = i & 63;
        float4 f0, f1, f2;
        if (nodeBase + n < N) {
            float2 a0 = __half22float2(*(const __half2*)(p0 + i));
            float2 a1 = __half22float2(*(const __half2*)(p0 + i + 2));
            float2 b0 = __half22float2(*(const __half2*)(p1 + i));
            float2 b1 = __half22float2(*(const __half2*)(p1 + i + 2));
            float2 c0 = __half22float2(*(const __half2*)(p2 + i));
            float2 c1 = __half22float2(*(const __half2*)(p2 + i + 2));
            f0 = make_float4(a0.x, a0.y, a1.x, a1.y);
            f1 = make_float4(b0.x, b0.y, b1.x, b1.y);
            f2 = make_float4(c0.x, c0.y, c1.x, c1.y);
        } else {
            f0 = f1 = f2 = make_float4(0.f, 0.f, 0.f, 0.f);
        }
        *(float4*)&sh[w][n][c]       = f0;
        *(float4*)&sh[w][n][64 + c]  = f1;
        *(float4*)&sh[w][n][128 + c] = f2;
    }
    __syncthreads();

    float bb = b[lane];
    float acc[8];
#pragma unroll
    for (int n = 0; n < 8; n++) acc[n] = bb;

#pragma unroll 4
    for (int j = 0; j < 192; j += 4) {
        float w0 = W[(j + 0) * NCH + lane];
        float w1 = W[(j + 1) * NCH + lane];
        float w2 = W[(j + 2) * NCH + lane];
        float w3 = W[(j + 3) * NCH + lane];
#pragma unroll
        for (int n = 0; n < 8; n++) {
            float4 tn = *(const float4*)&sh[w][n][j];
            acc[n] = fmaf(tn.x, w0, acc[n]);
            acc[n] = fmaf(tn.y, w1, acc[n]);
            acc[n] = fmaf(tn.z, w2, acc[n]);
            acc[n] = fmaf(tn.w, w3, acc[n]);
        }
    }

    float s = 0.f, q = 0.f;
#pragma unroll
    for (int n = 0; n < 8; n++) {
        float a = fmaxf(acc[n], 0.0f);
        if (nodeBase + n < N) {
            out[(size_t)(nodeBase + n) * NCH + lane] = (TOUT)a;
            s += a;
            q = fmaf(a, a, q);
        }
    }
    red[w][lane] = s;
    red[w][64 + lane] = q;
    __syncthreads();
    if (w == 0) {
        float S = red[0][lane] + red[1][lane] + red[2][lane] + red[3][lane];
        float Q = red[0][64 + lane] + red[1][64 + lane] + red[2][64 + lane] + red[3][64 + lane];
        int bank = blockIdx.x & (SBANKS - 1);
        atomicAdd(&statsP[bank * 128 + lane], S);
        atomicAdd(&statsP[bank * 128 + 64 + lane], Q);
    }
}

// reduce SBANKS partials -> mean/rstd at statsP[SBANKS*128 + {c, 64+c}]
__global__ void k_final(float* __restrict__ statsP, float invN) {
    int c = threadIdx.x;  // 64
    float S = 0.f, Q = 0.f;
    for (int k = 0; k < SBANKS; k++) {
        S += statsP[k * 128 + c];
        Q += statsP[k * 128 + 64 + c];
    }
    float m = S * invN;
    float var = Q * invN - m * m;
    statsP[SBANKS * 128 + c] = m;
    statsP[SBANKS * 128 + 64 + c] = rsqrtf(var + EPS);
}

__global__ void k_norm_h(__half* __restrict__ h, const float* __restrict__ statsP, int total) {
    int i = blockIdx.x * blockDim.x + threadIdx.x;
    if (i >= total) return;
    int lane = i & 63;
    h[i] = __float2half((__half2float(h[i]) - statsP[SBANKS * 128 + lane]) * statsP[SBANKS * 128 + 64 + lane]);
}

__global__ void k_norm_f(float* __restrict__ h, const float* __restrict__ statsP, int total) {
    int i = blockIdx.x * blockDim.x + threadIdx.x;
    if (i >= total) return;
    int lane = i & 63;
    h[i] = (h[i] - statsP[SBANKS * 128 + lane]) * statsP[SBANKS * 128 + 64 + lane];
}

// ---------------- launcher ----------------
extern "C" void kernel_launch(void* const* d_in, const int* in_sizes, int n_in,
                              void* d_out, int out_size, void* d_ws, size_t ws_size,
                              hipStream_t stream) {
    const float* x  = (const float*)d_in[0];
    const int*   ei = (const int*)d_in[1];
    const float* W1 = (const float*)d_in[2];
    const float* b1 = (const float*)d_in[3];
    const float* W2 = (const float*)d_in[4];
    const float* b2 = (const float*)d_in[5];
    float* out = (float*)d_out;

    const int N = in_sizes[0] / NCH;
    const int E = in_sizes[1] / 2;
    const int* src = ei;
    const int* dst = ei + E;

    // workspace carve (256B aligned)
    char* p = (char*)d_ws;
    auto alloc = [&](size_t bytes) {
        void* r = (void*)p;
        p += ((bytes + 255) / 256) * 256;
        return r;
    };
    int*    deg      = (int*)alloc((size_t)N * 4);
    float*  dinv     = (float*)alloc((size_t)N * 4);
    int*    rowstart = (int*)alloc((size_t)(N + 1) * 4);
    int*    cursor   = (int*)alloc((size_t)N * 4);
    const int NB1 = (N + 255) / 256;
    int*    bsum     = (int*)alloc((size_t)NB1 * 4);
    int2*   csr      = (int2*)alloc((size_t)E * 8);
    __half* xh       = (__half*)alloc((size_t)N * NCH * 2);
    __half* Tx1      = (__half*)alloc((size_t)N * NCH * 2);
    __half* Tx2      = (__half*)alloc((size_t)N * NCH * 2);
    __half* A        = (__half*)alloc((size_t)N * NCH * 2);
    const int statsFloats = SBANKS * 128 + 128;
    float*  stats1   = (float*)alloc((size_t)statsFloats * 4);
    float*  stats2   = (float*)alloc((size_t)statsFloats * 4);

    hipMemsetAsync(deg, 0, (size_t)N * 4, stream);
    hipMemsetAsync(cursor, 0, (size_t)N * 4, stream);
    hipMemsetAsync(stats1, 0, (size_t)statsFloats * 4, stream);
    hipMemsetAsync(stats2, 0, (size_t)statsFloats * 4, stream);

    const int TB = 256;
    const int npp = (N + NPASS - 1) / NPASS;
    // build CSR (by dst) + edge weights
    k_deg<<<(E + TB - 1) / TB, TB, 0, stream>>>(dst, deg, E);
    k_dinv<<<(N + TB - 1) / TB, TB, 0, stream>>>(deg, dinv, N);
    k_scan1<<<NB1, 256, 0, stream>>>(deg, bsum, N);
    k_scan2<<<1, 512, 0, stream>>>(bsum, NB1);
    k_scan3<<<NB1, 256, 0, stream>>>(deg, bsum, rowstart, N, E);
    k_fill_mp<<<2048, TB, 0, stream>>>(src, dst, dinv, rowstart, cursor, csr, E, npp);
    k_cast<<<(N * NCH + TB - 1) / TB, TB, 0, stream>>>(x, xh, N * NCH);

    const int propBlocks = (N * NCH + TB - 1) / TB;
    const int denseBlocks = (N + 31) / 32;
    const int normBlocks = (N * NCH + TB - 1) / TB;
    const float invN = 1.0f / (float)N;

    // ---- layer 1 ----
    k_prop<<<propBlocks, TB, 0, stream>>>(xh, rowstart, csr, nullptr, Tx1, N);
    k_prop<<<propBlocks, TB, 0, stream>>>(Tx1, rowstart, csr, xh, Tx2, N);
    k_dense<__half><<<denseBlocks, TB, 0, stream>>>(xh, Tx1, Tx2, W1, b1, A, stats1, N);
    k_final<<<1, 64, 0, stream>>>(stats1, invN);
    k_norm_h<<<normBlocks, TB, 0, stream>>>(A, stats1, N * NCH);

    // ---- layer 2 ----
    k_prop<<<propBlocks, TB, 0, stream>>>(A, rowstart, csr, nullptr, Tx1, N);
    k_prop<<<propBlocks, TB, 0, stream>>>(Tx1, rowstart, csr, A, Tx2, N);
    k_dense<float><<<denseBlocks, TB, 0, stream>>>(A, Tx1, Tx2, W2, b2, out, stats2, N);
    k_final<<<1, 64, 0, stream>>>(stats2, invN);
    k_norm_f<<<normBlocks, TB, 0, stream>>>(out, stats2, N * NCH);
}

// Round 4
// 562.146 us; speedup vs baseline: 1.5405x; 1.1707x over previous
//
#include <hip/hip_runtime.h>
#include <hip/hip_fp16.h>

#define NCH 64
#define EPS 1e-5f
#define SBANKS 32   // stats atomic banks

// ---------------- XCD-pinned degree histogram ----------------
// blockIdx&7 -> XCD (dispatch round-robin heuristic); each XCD owns a 1/8 dst
// range so its deg slice (~50KB) stays in its own L2. Correctness does not
// depend on the mapping (atomics + deterministic partition).
__global__ __launch_bounds__(256) void k_deg_x(const int* __restrict__ dst,
                                               int* __restrict__ deg, int E, int N, int npp8) {
    int xcd = blockIdx.x & 7;
    int lo = xcd * npp8;
    int hi = min(lo + npp8, N);
    int q = blockIdx.x >> 3, nq = gridDim.x >> 3;
    for (int e = q * 256 + threadIdx.x; e < E; e += nq * 256) {
        int d = dst[e];
        if (d >= lo && d < hi) atomicAdd(&deg[d], 1);
    }
}

__global__ void k_dinv(const int* __restrict__ deg, float* __restrict__ dinv, int N) {
    int i = blockIdx.x * blockDim.x + threadIdx.x;
    if (i < N) {
        int d = deg[i];
        dinv[i] = (d > 0) ? rsqrtf((float)d) : 0.0f;
    }
}

// ---------------- fp32 -> fp16 cast ----------------
__global__ void k_cast(const float* __restrict__ x, __half* __restrict__ xh, int total) {
    int i = blockIdx.x * blockDim.x + threadIdx.x;
    if (i < total) xh[i] = __float2half(x[i]);
}

// ---------------- 3-kernel exclusive scan of deg -> rowstart ----------------
__global__ void k_scan1(const int* __restrict__ deg, int* __restrict__ bsum, int N) {
    __shared__ int s[256];
    int t = threadIdx.x;
    int i = blockIdx.x * 256 + t;
    s[t] = (i < N) ? deg[i] : 0;
    __syncthreads();
    for (int off = 128; off > 0; off >>= 1) {
        if (t < off) s[t] += s[t + off];
        __syncthreads();
    }
    if (t == 0) bsum[blockIdx.x] = s[0];
}

__global__ void k_scan2(int* __restrict__ bsum, int NB) {
    __shared__ int s[512];
    int t = threadIdx.x;
    int v = (t < NB) ? bsum[t] : 0;
    s[t] = v;
    __syncthreads();
    for (int off = 1; off < 512; off <<= 1) {
        int add = (t >= off) ? s[t - off] : 0;
        __syncthreads();
        s[t] += add;
        __syncthreads();
    }
    if (t < NB) bsum[t] = s[t] - v;  // exclusive
}

__global__ void k_scan3(const int* __restrict__ deg, const int* __restrict__ bsum,
                        int* __restrict__ rowstart, int N, int E) {
    __shared__ int s[256];
    int t = threadIdx.x;
    int i = blockIdx.x * 256 + t;
    int v = (i < N) ? deg[i] : 0;
    s[t] = v;
    __syncthreads();
    for (int off = 1; off < 256; off <<= 1) {
        int add = (t >= off) ? s[t - off] : 0;
        __syncthreads();
        s[t] += add;
        __syncthreads();
    }
    if (i < N) rowstart[i] = bsum[blockIdx.x] + (s[t] - v);
    if (i == N - 1) rowstart[N] = E;
}

// ---------------- XCD-pinned CSR fill ----------------
// Each XCD scans all edges but only claims dst in its 1/8 range: its 1.6MB CSR
// slice + cursor slice live in its own L2, so scattered 8B writes combine into
// full 64B lines before eviction (fixes the 8x write amplification).
__global__ __launch_bounds__(256) void k_fill_x(const int* __restrict__ src,
                                                const int* __restrict__ dst,
                                                const float* __restrict__ dinv,
                                                const int* __restrict__ rowstart,
                                                int* __restrict__ cursor,
                                                int2* __restrict__ csr, int E, int N, int npp8) {
    int xcd = blockIdx.x & 7;
    int lo = xcd * npp8;
    int hi = min(lo + npp8, N);
    int q = blockIdx.x >> 3, nq = gridDim.x >> 3;
    for (int e = q * 256 + threadIdx.x; e < E; e += nq * 256) {
        int d = dst[e];
        if (d < lo || d >= hi) continue;
        int s = src[e];
        float w = -dinv[s] * dinv[d];
        int pos = atomicAdd(&cursor[d], 1);
        csr[rowstart[d] + pos] = make_int2(s, __float_as_int(w));
    }
}

// ---------------- propagation: y = prop(h)  (or 2*prop(h) - tx0) ----------------
// 2 dst nodes per wave: 32 lanes x half2 per node. fp32 accumulate.
__global__ __launch_bounds__(256) void k_prop(const __half* __restrict__ h,
                                              const int* __restrict__ rowstart,
                                              const int2* __restrict__ csr,
                                              const __half* __restrict__ tx0,
                                              __half* __restrict__ y, int N) {
    int gid = blockIdx.x * blockDim.x + threadIdx.x;
    int wave = gid >> 6;
    int lane = gid & 63;
    int node = wave * 2 + (lane >> 5);
    int c2 = lane & 31;  // half2 column: channels 2*c2, 2*c2+1
    if (node >= N) return;
    const __half2* h2 = (const __half2*)h;
    int e = rowstart[node];
    int e1 = rowstart[node + 1];
    float ax = 0.0f, ay = 0.0f;
    for (; e + 4 <= e1; e += 4) {
        int2 k0 = csr[e], k1 = csr[e + 1], k2 = csr[e + 2], k3 = csr[e + 3];
        __half2 g0 = h2[k0.x * 32 + c2];
        __half2 g1 = h2[k1.x * 32 + c2];
        __half2 g2 = h2[k2.x * 32 + c2];
        __half2 g3 = h2[k3.x * 32 + c2];
        float2 f0 = __half22float2(g0);
        float2 f1 = __half22float2(g1);
        float2 f2 = __half22float2(g2);
        float2 f3 = __half22float2(g3);
        float w0 = __int_as_float(k0.y), w1 = __int_as_float(k1.y);
        float w2 = __int_as_float(k2.y), w3 = __int_as_float(k3.y);
        ax = fmaf(w0, f0.x, ax); ay = fmaf(w0, f0.y, ay);
        ax = fmaf(w1, f1.x, ax); ay = fmaf(w1, f1.y, ay);
        ax = fmaf(w2, f2.x, ax); ay = fmaf(w2, f2.y, ay);
        ax = fmaf(w3, f3.x, ax); ay = fmaf(w3, f3.y, ay);
    }
    for (; e < e1; e++) {
        int2 k = csr[e];
        float2 f = __half22float2(h2[k.x * 32 + c2]);
        float w = __int_as_float(k.y);
        ax = fmaf(w, f.x, ax); ay = fmaf(w, f.y, ay);
    }
    if (tx0 != nullptr) {
        float2 t = __half22float2(((const __half2*)tx0)[node * 32 + c2]);
        ax = 2.0f * ax - t.x;
        ay = 2.0f * ay - t.y;
    }
    ((__half2*)y)[node * 32 + c2] = __floats2half2_rn(ax, ay);
}

// ---------------- dense combine + ReLU + banked instance-norm stats ----------------
// one wave per 8 nodes (32/block); lane = output channel; W flattened [192][64]
template <typename TOUT>
__global__ __launch_bounds__(256) void k_dense(const __half* __restrict__ tx0,
                                               const __half* __restrict__ tx1,
                                               const __half* __restrict__ tx2,
                                               const float* __restrict__ W,
                                               const float* __restrict__ b,
                                               TOUT* __restrict__ out,
                                               float* __restrict__ statsP, int N) {
    __shared__ float sh[4][8][192];   // 24576 B
    __shared__ float red[4][128];     //  2048 B
    int t = threadIdx.x;
    int w = t >> 6;
    int lane = t & 63;
    int nodeBase = blockIdx.x * 32 + w * 8;

    const __half* p0 = tx0 + (size_t)nodeBase * NCH;
    const __half* p1 = tx1 + (size_t)nodeBase * NCH;
    const __half* p2 = tx2 + (size_t)nodeBase * NCH;
#pragma unroll
    for (int v = 0; v < 2; v++) {
        int i = v * 256 + lane * 4;
        int n = i >> 6, c = i & 63;
        float4 f0, f1, f2;
        if (nodeBase + n < N) {
            float2 a0 = __half22float2(*(const __half2*)(p0 + i));
            float2 a1 = __half22float2(*(const __half2*)(p0 + i + 2));
            float2 b0 = __half22float2(*(const __half2*)(p1 + i));
            float2 b1 = __half22float2(*(const __half2*)(p1 + i + 2));
            float2 c0 = __half22float2(*(const __half2*)(p2 + i));
            float2 c1 = __half22float2(*(const __half2*)(p2 + i + 2));
            f0 = make_float4(a0.x, a0.y, a1.x, a1.y);
            f1 = make_float4(b0.x, b0.y, b1.x, b1.y);
            f2 = make_float4(c0.x, c0.y, c1.x, c1.y);
        } else {
            f0 = f1 = f2 = make_float4(0.f, 0.f, 0.f, 0.f);
        }
        *(float4*)&sh[w][n][c]       = f0;
        *(float4*)&sh[w][n][64 + c]  = f1;
        *(float4*)&sh[w][n][128 + c] = f2;
    }
    __syncthreads();

    float bb = b[lane];
    float acc[8];
#pragma unroll
    for (int n = 0; n < 8; n++) acc[n] = bb;

#pragma unroll 4
    for (int j = 0; j < 192; j += 4) {
        float w0 = W[(j + 0) * NCH + lane];
        float w1 = W[(j + 1) * NCH + lane];
        float w2 = W[(j + 2) * NCH + lane];
        float w3 = W[(j + 3) * NCH + lane];
#pragma unroll
        for (int n = 0; n < 8; n++) {
            float4 tn = *(const float4*)&sh[w][n][j];
            acc[n] = fmaf(tn.x, w0, acc[n]);
            acc[n] = fmaf(tn.y, w1, acc[n]);
            acc[n] = fmaf(tn.z, w2, acc[n]);
            acc[n] = fmaf(tn.w, w3, acc[n]);
        }
    }

    float s = 0.f, q = 0.f;
#pragma unroll
    for (int n = 0; n < 8; n++) {
        float a = fmaxf(acc[n], 0.0f);
        if (nodeBase + n < N) {
            out[(size_t)(nodeBase + n) * NCH + lane] = (TOUT)a;
            s += a;
            q = fmaf(a, a, q);
        }
    }
    red[w][lane] = s;
    red[w][64 + lane] = q;
    __syncthreads();
    if (w == 0) {
        float S = red[0][lane] + red[1][lane] + red[2][lane] + red[3][lane];
        float Q = red[0][64 + lane] + red[1][64 + lane] + red[2][64 + lane] + red[3][64 + lane];
        int bank = blockIdx.x & (SBANKS - 1);
        atomicAdd(&statsP[bank * 128 + lane], S);
        atomicAdd(&statsP[bank * 128 + 64 + lane], Q);
    }
}

// reduce SBANKS partials -> mean/rstd at statsP[SBANKS*128 + {c, 64+c}]
__global__ void k_final(float* __restrict__ statsP, float invN) {
    int c = threadIdx.x;  // 64
    float S = 0.f, Q = 0.f;
    for (int k = 0; k < SBANKS; k++) {
        S += statsP[k * 128 + c];
        Q += statsP[k * 128 + 64 + c];
    }
    float m = S * invN;
    float var = Q * invN - m * m;
    statsP[SBANKS * 128 + c] = m;
    statsP[SBANKS * 128 + 64 + c] = rsqrtf(var + EPS);
}

__global__ void k_norm_h(__half* __restrict__ h, const float* __restrict__ statsP, int total) {
    int i = blockIdx.x * blockDim.x + threadIdx.x;
    if (i >= total) return;
    int lane = i & 63;
    h[i] = __float2half((__half2float(h[i]) - statsP[SBANKS * 128 + lane]) * statsP[SBANKS * 128 + 64 + lane]);
}

__global__ void k_norm_f(float* __restrict__ h, const float* __restrict__ statsP, int total) {
    int i = blockIdx.x * blockDim.x + threadIdx.x;
    if (i >= total) return;
    int lane = i & 63;
    h[i] = (h[i] - statsP[SBANKS * 128 + lane]) * statsP[SBANKS * 128 + 64 + lane];
}

// ---------------- launcher ----------------
extern "C" void kernel_launch(void* const* d_in, const int* in_sizes, int n_in,
                              void* d_out, int out_size, void* d_ws, size_t ws_size,
                              hipStream_t stream) {
    const float* x  = (const float*)d_in[0];
    const int*   ei = (const int*)d_in[1];
    const float* W1 = (const float*)d_in[2];
    const float* b1 = (const float*)d_in[3];
    const float* W2 = (const float*)d_in[4];
    const float* b2 = (const float*)d_in[5];
    float* out = (float*)d_out;

    const int N = in_sizes[0] / NCH;
    const int E = in_sizes[1] / 2;
    const int* src = ei;
    const int* dst = ei + E;

    // workspace carve (256B aligned)
    char* p = (char*)d_ws;
    auto alloc = [&](size_t bytes) {
        void* r = (void*)p;
        p += ((bytes + 255) / 256) * 256;
        return r;
    };
    int*    deg      = (int*)alloc((size_t)N * 4);
    float*  dinv     = (float*)alloc((size_t)N * 4);
    int*    rowstart = (int*)alloc((size_t)(N + 1) * 4);
    int*    cursor   = (int*)alloc((size_t)N * 4);
    const int NB1 = (N + 255) / 256;
    int*    bsum     = (int*)alloc((size_t)NB1 * 4);
    int2*   csr      = (int2*)alloc((size_t)E * 8);
    __half* xh       = (__half*)alloc((size_t)N * NCH * 2);
    __half* Tx1      = (__half*)alloc((size_t)N * NCH * 2);
    __half* Tx2      = (__half*)alloc((size_t)N * NCH * 2);
    __half* A        = (__half*)alloc((size_t)N * NCH * 2);
    const int statsFloats = SBANKS * 128 + 128;
    float*  stats1   = (float*)alloc((size_t)statsFloats * 4);
    float*  stats2   = (float*)alloc((size_t)statsFloats * 4);

    hipMemsetAsync(deg, 0, (size_t)N * 4, stream);
    hipMemsetAsync(cursor, 0, (size_t)N * 4, stream);
    hipMemsetAsync(stats1, 0, (size_t)statsFloats * 4, stream);
    hipMemsetAsync(stats2, 0, (size_t)statsFloats * 4, stream);

    const int TB = 256;
    const int npp8 = (N + 7) / 8;
    k_deg_x<<<2048, TB, 0, stream>>>(dst, deg, E, N, npp8);
    k_dinv<<<(N + TB - 1) / TB, TB, 0, stream>>>(deg, dinv, N);
    k_scan1<<<NB1, 256, 0, stream>>>(deg, bsum, N);
    k_scan2<<<1, 512, 0, stream>>>(bsum, NB1);
    k_scan3<<<NB1, 256, 0, stream>>>(deg, bsum, rowstart, N, E);
    k_fill_x<<<2048, TB, 0, stream>>>(src, dst, dinv, rowstart, cursor, csr, E, N, npp8);
    k_cast<<<(N * NCH + TB - 1) / TB, TB, 0, stream>>>(x, xh, N * NCH);

    const int propBlocks = ((N + 1) / 2 * 64 + TB - 1) / TB;
    const int denseBlocks = (N + 31) / 32;
    const int normBlocks = (N * NCH + TB - 1) / TB;
    const float invN = 1.0f / (float)N;

    // ---- layer 1 ----
    k_prop<<<propBlocks, TB, 0, stream>>>(xh, rowstart, csr, nullptr, Tx1, N);
    k_prop<<<propBlocks, TB, 0, stream>>>(Tx1, rowstart, csr, xh, Tx2, N);
    k_dense<__half><<<denseBlocks, TB, 0, stream>>>(xh, Tx1, Tx2, W1, b1, A, stats1, N);
    k_final<<<1, 64, 0, stream>>>(stats1, invN);
    k_norm_h<<<normBlocks, TB, 0, stream>>>(A, stats1, N * NCH);

    // ---- layer 2 ----
    k_prop<<<propBlocks, TB, 0, stream>>>(A, rowstart, csr, nullptr, Tx1, N);
    k_prop<<<propBlocks, TB, 0, stream>>>(Tx1, rowstart, csr, A, Tx2, N);
    k_dense<float><<<denseBlocks, TB, 0, stream>>>(A, Tx1, Tx2, W2, b2, out, stats2, N);
    k_final<<<1, 64, 0, stream>>>(stats2, invN);
    k_norm_f<<<normBlocks, TB, 0, stream>>>(out, stats2, N * NCH);
}

// Round 5
// 477.875 us; speedup vs baseline: 1.8122x; 1.1763x over previous
//
#include <hip/hip_runtime.h>
#include <hip/hip_fp16.h>

#define NCH 64
#define EPS 1e-5f
#define SBANKS 32   // stats atomic banks
#define BSHIFT 8    // 256 dst nodes per bucket
#define NBLKA 256   // blocks in hist/bin passes

// ---------------- Phase A1: bucket histogram ----------------
__global__ __launch_bounds__(256) void k_hist(const int* __restrict__ dst,
                                              int* __restrict__ cnt, int E, int per, int nbuck) {
    __shared__ int lh[512];
    for (int t = threadIdx.x; t < nbuck; t += 256) lh[t] = 0;
    __syncthreads();
    int lo = blockIdx.x * per, hi = min(E, lo + per);
    for (int e = lo + threadIdx.x; e < hi; e += 256)
        atomicAdd(&lh[dst[e] >> BSHIFT], 1);
    __syncthreads();
    for (int t = threadIdx.x; t < nbuck; t += 256)
        if (lh[t]) atomicAdd(&cnt[t], lh[t]);
}

// ---------------- Phase A: scan bucket counts -> base & cursor ----------------
__global__ void k_bscan(const int* __restrict__ cnt, int* __restrict__ gbase,
                        int* __restrict__ gcur, int nbuck, int E) {
    __shared__ int s[512];
    int t = threadIdx.x;
    int v = (t < nbuck) ? cnt[t] : 0;
    s[t] = v;
    __syncthreads();
    for (int off = 1; off < 512; off <<= 1) {
        int add = (t >= off) ? s[t - off] : 0;
        __syncthreads();
        s[t] += add;
        __syncthreads();
    }
    if (t < nbuck) { int ex = s[t] - v; gbase[t] = ex; gcur[t] = ex; }
    if (t == 0) gbase[nbuck] = E;
}

// ---------------- Phase A2: bin edges into bucket segments ----------------
// Per-block histogram -> one global atomicAdd per (block,bucket) reserves a
// contiguous run (~128B) -> appends are line-local, no 8x write amplification.
__global__ __launch_bounds__(256) void k_bin(const int* __restrict__ src,
                                             const int* __restrict__ dst,
                                             int* __restrict__ gcur,
                                             int2* __restrict__ binned, int E, int per, int nbuck) {
    __shared__ int lh[512];
    __shared__ int lcur[512];
    for (int t = threadIdx.x; t < nbuck; t += 256) lh[t] = 0;
    __syncthreads();
    int lo = blockIdx.x * per, hi = min(E, lo + per);
    for (int e = lo + threadIdx.x; e < hi; e += 256)
        atomicAdd(&lh[dst[e] >> BSHIFT], 1);
    __syncthreads();
    for (int t = threadIdx.x; t < nbuck; t += 256) {
        int c = lh[t];
        lcur[t] = c ? atomicAdd(&gcur[t], c) : 0;
    }
    __syncthreads();
    for (int e = lo + threadIdx.x; e < hi; e += 256) {
        int d = dst[e];
        int b = d >> BSHIFT;
        int pos = atomicAdd(&lcur[b], 1);
        binned[pos] = make_int2(src[e], d);
    }
}

// ---------------- Phase B: per-bucket CSR build (single-writer regions) ----------------
// One workgroup per bucket: LDS histogram -> deg/dinv + rowstart (coalesced),
// then scatter into this bucket's private ~32KB CSR slice (stays in one L2,
// lines fill completely). Stores (src, -dinv[dst]); dinv[src] applied in phase C.
__global__ __launch_bounds__(256) void k_bucket(const int2* __restrict__ binned,
                                                const int* __restrict__ gbase,
                                                float* __restrict__ dinv,
                                                int* __restrict__ rowstart,
                                                int2* __restrict__ csr, int N, int nbuck, int E) {
    __shared__ int hist[256];
    __shared__ float ldinv[256];
    __shared__ int lcur[256];
    __shared__ int ltmp[256];
    int b = blockIdx.x;
    int t = threadIdx.x;
    int nodeLo = b << BSHIFT;
    int nHere = min(256, N - nodeLo);
    int e0 = gbase[b], e1 = gbase[b + 1];
    hist[t] = 0;
    __syncthreads();
    for (int e = e0 + t; e < e1; e += 256)
        atomicAdd(&hist[binned[e].y - nodeLo], 1);
    __syncthreads();
    int deg = (t < nHere) ? hist[t] : 0;
    float di = (deg > 0) ? rsqrtf((float)deg) : 0.0f;
    if (t < nHere) { dinv[nodeLo + t] = di; }
    ldinv[t] = di;
    // exclusive scan of deg -> local row starts
    ltmp[t] = deg;
    __syncthreads();
    for (int off = 1; off < 256; off <<= 1) {
        int add = (t >= off) ? ltmp[t - off] : 0;
        __syncthreads();
        ltmp[t] += add;
        __syncthreads();
    }
    int lstart = ltmp[t] - deg;
    if (t < nHere) rowstart[nodeLo + t] = e0 + lstart;
    if (b == nbuck - 1 && t == 0) rowstart[N] = E;
    lcur[t] = lstart;
    __syncthreads();
    for (int e = e0 + t; e < e1; e += 256) {
        int2 sd = binned[e];
        int dl = sd.y - nodeLo;
        int pos = atomicAdd(&lcur[dl], 1);
        csr[e0 + pos] = make_int2(sd.x, __float_as_int(-ldinv[dl]));
    }
}

// ---------------- Phase C: apply dinv[src] ----------------
__global__ void k_weights(int2* __restrict__ csr, const float* __restrict__ dinv, int E) {
    int e = blockIdx.x * blockDim.x + threadIdx.x;
    if (e < E) {
        int2 c = csr[e];
        float w = __int_as_float(c.y) * dinv[c.x];
        csr[e] = make_int2(c.x, __float_as_int(w));
    }
}

// ---------------- fp32 -> fp16 cast ----------------
__global__ void k_cast(const float* __restrict__ x, __half* __restrict__ xh, int total) {
    int i = blockIdx.x * blockDim.x + threadIdx.x;
    if (i < total) xh[i] = __float2half(x[i]);
}

// ---------------- propagation: y = prop(h)  (or 2*prop(h) - tx0) ----------------
// 2 dst nodes per wave: 32 lanes x half2 per node. fp32 accumulate.
__global__ __launch_bounds__(256) void k_prop(const __half* __restrict__ h,
                                              const int* __restrict__ rowstart,
                                              const int2* __restrict__ csr,
                                              const __half* __restrict__ tx0,
                                              __half* __restrict__ y, int N) {
    int gid = blockIdx.x * blockDim.x + threadIdx.x;
    int wave = gid >> 6;
    int lane = gid & 63;
    int node = wave * 2 + (lane >> 5);
    int c2 = lane & 31;
    if (node >= N) return;
    const __half2* h2 = (const __half2*)h;
    int e = rowstart[node];
    int e1 = rowstart[node + 1];
    float ax = 0.0f, ay = 0.0f;
    for (; e + 4 <= e1; e += 4) {
        int2 k0 = csr[e], k1 = csr[e + 1], k2 = csr[e + 2], k3 = csr[e + 3];
        __half2 g0 = h2[k0.x * 32 + c2];
        __half2 g1 = h2[k1.x * 32 + c2];
        __half2 g2 = h2[k2.x * 32 + c2];
        __half2 g3 = h2[k3.x * 32 + c2];
        float2 f0 = __half22float2(g0);
        float2 f1 = __half22float2(g1);
        float2 f2 = __half22float2(g2);
        float2 f3 = __half22float2(g3);
        float w0 = __int_as_float(k0.y), w1 = __int_as_float(k1.y);
        float w2 = __int_as_float(k2.y), w3 = __int_as_float(k3.y);
        ax = fmaf(w0, f0.x, ax); ay = fmaf(w0, f0.y, ay);
        ax = fmaf(w1, f1.x, ax); ay = fmaf(w1, f1.y, ay);
        ax = fmaf(w2, f2.x, ax); ay = fmaf(w2, f2.y, ay);
        ax = fmaf(w3, f3.x, ax); ay = fmaf(w3, f3.y, ay);
    }
    for (; e < e1; e++) {
        int2 k = csr[e];
        float2 f = __half22float2(h2[k.x * 32 + c2]);
        float w = __int_as_float(k.y);
        ax = fmaf(w, f.x, ax); ay = fmaf(w, f.y, ay);
    }
    if (tx0 != nullptr) {
        float2 t = __half22float2(((const __half2*)tx0)[node * 32 + c2]);
        ax = 2.0f * ax - t.x;
        ay = 2.0f * ay - t.y;
    }
    ((__half2*)y)[node * 32 + c2] = __floats2half2_rn(ax, ay);
}

// ---------------- dense combine + ReLU + banked instance-norm stats ----------------
template <typename TOUT>
__global__ __launch_bounds__(256) void k_dense(const __half* __restrict__ tx0,
                                               const __half* __restrict__ tx1,
                                               const __half* __restrict__ tx2,
                                               const float* __restrict__ W,
                                               const float* __restrict__ b,
                                               TOUT* __restrict__ out,
                                               float* __restrict__ statsP, int N) {
    __shared__ float sh[4][8][192];
    __shared__ float red[4][128];
    int t = threadIdx.x;
    int w = t >> 6;
    int lane = t & 63;
    int nodeBase = blockIdx.x * 32 + w * 8;

    const __half* p0 = tx0 + (size_t)nodeBase * NCH;
    const __half* p1 = tx1 + (size_t)nodeBase * NCH;
    const __half* p2 = tx2 + (size_t)nodeBase * NCH;
#pragma unroll
    for (int v = 0; v < 2; v++) {
        int i = v * 256 + lane * 4;
        int n = i >> 6, c = i & 63;
        float4 f0, f1, f2;
        if (nodeBase + n < N) {
            float2 a0 = __half22float2(*(const __half2*)(p0 + i));
            float2 a1 = __half22float2(*(const __half2*)(p0 + i + 2));
            float2 b0 = __half22float2(*(const __half2*)(p1 + i));
            float2 b1 = __half22float2(*(const __half2*)(p1 + i + 2));
            float2 c0 = __half22float2(*(const __half2*)(p2 + i));
            float2 c1 = __half22float2(*(const __half2*)(p2 + i + 2));
            f0 = make_float4(a0.x, a0.y, a1.x, a1.y);
            f1 = make_float4(b0.x, b0.y, b1.x, b1.y);
            f2 = make_float4(c0.x, c0.y, c1.x, c1.y);
        } else {
            f0 = f1 = f2 = make_float4(0.f, 0.f, 0.f, 0.f);
        }
        *(float4*)&sh[w][n][c]       = f0;
        *(float4*)&sh[w][n][64 + c]  = f1;
        *(float4*)&sh[w][n][128 + c] = f2;
    }
    __syncthreads();

    float bb = b[lane];
    float acc[8];
#pragma unroll
    for (int n = 0; n < 8; n++) acc[n] = bb;

#pragma unroll 4
    for (int j = 0; j < 192; j += 4) {
        float w0 = W[(j + 0) * NCH + lane];
        float w1 = W[(j + 1) * NCH + lane];
        float w2 = W[(j + 2) * NCH + lane];
        float w3 = W[(j + 3) * NCH + lane];
#pragma unroll
        for (int n = 0; n < 8; n++) {
            float4 tn = *(const float4*)&sh[w][n][j];
            acc[n] = fmaf(tn.x, w0, acc[n]);
            acc[n] = fmaf(tn.y, w1, acc[n]);
            acc[n] = fmaf(tn.z, w2, acc[n]);
            acc[n] = fmaf(tn.w, w3, acc[n]);
        }
    }

    float s = 0.f, q = 0.f;
#pragma unroll
    for (int n = 0; n < 8; n++) {
        float a = fmaxf(acc[n], 0.0f);
        if (nodeBase + n < N) {
            out[(size_t)(nodeBase + n) * NCH + lane] = (TOUT)a;
            s += a;
            q = fmaf(a, a, q);
        }
    }
    red[w][lane] = s;
    red[w][64 + lane] = q;
    __syncthreads();
    if (w == 0) {
        float S = red[0][lane] + red[1][lane] + red[2][lane] + red[3][lane];
        float Q = red[0][64 + lane] + red[1][64 + lane] + red[2][64 + lane] + red[3][64 + lane];
        int bank = blockIdx.x & (SBANKS - 1);
        atomicAdd(&statsP[bank * 128 + lane], S);
        atomicAdd(&statsP[bank * 128 + 64 + lane], Q);
    }
}

__global__ void k_final(float* __restrict__ statsP, float invN) {
    int c = threadIdx.x;  // 64
    float S = 0.f, Q = 0.f;
    for (int k = 0; k < SBANKS; k++) {
        S += statsP[k * 128 + c];
        Q += statsP[k * 128 + 64 + c];
    }
    float m = S * invN;
    float var = Q * invN - m * m;
    statsP[SBANKS * 128 + c] = m;
    statsP[SBANKS * 128 + 64 + c] = rsqrtf(var + EPS);
}

__global__ void k_norm_h(__half* __restrict__ h, const float* __restrict__ statsP, int total) {
    int i = blockIdx.x * blockDim.x + threadIdx.x;
    if (i >= total) return;
    int lane = i & 63;
    h[i] = __float2half((__half2float(h[i]) - statsP[SBANKS * 128 + lane]) * statsP[SBANKS * 128 + 64 + lane]);
}

__global__ void k_norm_f(float* __restrict__ h, const float* __restrict__ statsP, int total) {
    int i = blockIdx.x * blockDim.x + threadIdx.x;
    if (i >= total) return;
    int lane = i & 63;
    h[i] = (h[i] - statsP[SBANKS * 128 + lane]) * statsP[SBANKS * 128 + 64 + lane];
}

// ---------------- launcher ----------------
extern "C" void kernel_launch(void* const* d_in, const int* in_sizes, int n_in,
                              void* d_out, int out_size, void* d_ws, size_t ws_size,
                              hipStream_t stream) {
    const float* x  = (const float*)d_in[0];
    const int*   ei = (const int*)d_in[1];
    const float* W1 = (const float*)d_in[2];
    const float* b1 = (const float*)d_in[3];
    const float* W2 = (const float*)d_in[4];
    const float* b2 = (const float*)d_in[5];
    float* out = (float*)d_out;

    const int N = in_sizes[0] / NCH;
    const int E = in_sizes[1] / 2;
    const int* src = ei;
    const int* dst = ei + E;
    const int nbuck = (N + 255) >> BSHIFT;

    // workspace carve (256B aligned)
    char* p = (char*)d_ws;
    auto alloc = [&](size_t bytes) {
        void* r = (void*)p;
        p += ((bytes + 255) / 256) * 256;
        return r;
    };
    float*  dinv     = (float*)alloc((size_t)N * 4);
    int*    rowstart = (int*)alloc((size_t)(N + 1) * 4);
    int*    cnt      = (int*)alloc((size_t)nbuck * 4);
    int*    gbase    = (int*)alloc((size_t)(nbuck + 1) * 4);
    int*    gcur     = (int*)alloc((size_t)nbuck * 4);
    int2*   csr      = (int2*)alloc((size_t)E * 8);
    __half* xh       = (__half*)alloc((size_t)N * NCH * 2);
    __half* Tx1      = (__half*)alloc((size_t)N * NCH * 2);
    __half* Tx2      = (__half*)alloc((size_t)N * NCH * 2);
    __half* A        = (__half*)alloc((size_t)N * NCH * 2);
    const int statsFloats = SBANKS * 128 + 128;
    float*  stats1   = (float*)alloc((size_t)statsFloats * 4);
    float*  stats2   = (float*)alloc((size_t)statsFloats * 4);

    // binned aliases Tx1 (12.8MB each; binned dead before first k_prop writes Tx1)
    int2* binned = (int2*)Tx1;

    hipMemsetAsync(cnt, 0, (size_t)nbuck * 4, stream);
    hipMemsetAsync(stats1, 0, (size_t)statsFloats * 4, stream);
    hipMemsetAsync(stats2, 0, (size_t)statsFloats * 4, stream);

    const int TB = 256;
    const int per = (E + NBLKA - 1) / NBLKA;
    k_hist<<<NBLKA, TB, 0, stream>>>(dst, cnt, E, per, nbuck);
    k_bscan<<<1, 512, 0, stream>>>(cnt, gbase, gcur, nbuck, E);
    k_bin<<<NBLKA, TB, 0, stream>>>(src, dst, gcur, binned, E, per, nbuck);
    k_bucket<<<nbuck, TB, 0, stream>>>(binned, gbase, dinv, rowstart, csr, N, nbuck, E);
    k_weights<<<(E + TB - 1) / TB, TB, 0, stream>>>(csr, dinv, E);
    k_cast<<<(N * NCH + TB - 1) / TB, TB, 0, stream>>>(x, xh, N * NCH);

    const int propBlocks = ((N + 1) / 2 * 64 + TB - 1) / TB;
    const int denseBlocks = (N + 31) / 32;
    const int normBlocks = (N * NCH + TB - 1) / TB;
    const float invN = 1.0f / (float)N;

    // ---- layer 1 ----
    k_prop<<<propBlocks, TB, 0, stream>>>(xh, rowstart, csr, nullptr, Tx1, N);
    k_prop<<<propBlocks, TB, 0, stream>>>(Tx1, rowstart, csr, xh, Tx2, N);
    k_dense<__half><<<denseBlocks, TB, 0, stream>>>(xh, Tx1, Tx2, W1, b1, A, stats1, N);
    k_final<<<1, 64, 0, stream>>>(stats1, invN);
    k_norm_h<<<normBlocks, TB, 0, stream>>>(A, stats1, N * NCH);

    // ---- layer 2 ----
    k_prop<<<propBlocks, TB, 0, stream>>>(A, rowstart, csr, nullptr, Tx1, N);
    k_prop<<<propBlocks, TB, 0, stream>>>(Tx1, rowstart, csr, A, Tx2, N);
    k_dense<float><<<denseBlocks, TB, 0, stream>>>(A, Tx1, Tx2, W2, b2, out, stats2, N);
    k_final<<<1, 64, 0, stream>>>(stats2, invN);
    k_norm_f<<<normBlocks, TB, 0, stream>>>(out, stats2, N * NCH);
}

// Round 6
// 410.979 us; speedup vs baseline: 2.1072x; 1.1628x over previous
//
#include <hip/hip_runtime.h>
#include <hip/hip_fp16.h>

#define NCH 64
#define EPS 1e-5f
#define SBANKS 32   // stats atomic banks
#define BSHIFT 8    // 256 dst nodes per bucket
#define NBLKA 256   // blocks in hist/bin passes

typedef _Float16 f16x8 __attribute__((ext_vector_type(8)));
typedef float f32x4 __attribute__((ext_vector_type(4)));

// ---------------- Phase A1: bucket histogram ----------------
__global__ __launch_bounds__(256) void k_hist(const int* __restrict__ dst,
                                              int* __restrict__ cnt, int E, int per, int nbuck) {
    __shared__ int lh[512];
    for (int t = threadIdx.x; t < nbuck; t += 256) lh[t] = 0;
    __syncthreads();
    int lo = blockIdx.x * per, hi = min(E, lo + per);
    for (int e = lo + threadIdx.x; e < hi; e += 256)
        atomicAdd(&lh[dst[e] >> BSHIFT], 1);
    __syncthreads();
    for (int t = threadIdx.x; t < nbuck; t += 256)
        if (lh[t]) atomicAdd(&cnt[t], lh[t]);
}

// ---------------- Phase A: scan bucket counts -> base & cursor ----------------
__global__ void k_bscan(const int* __restrict__ cnt, int* __restrict__ gbase,
                        int* __restrict__ gcur, int nbuck, int E) {
    __shared__ int s[512];
    int t = threadIdx.x;
    int v = (t < nbuck) ? cnt[t] : 0;
    s[t] = v;
    __syncthreads();
    for (int off = 1; off < 512; off <<= 1) {
        int add = (t >= off) ? s[t - off] : 0;
        __syncthreads();
        s[t] += add;
        __syncthreads();
    }
    if (t < nbuck) { int ex = s[t] - v; gbase[t] = ex; gcur[t] = ex; }
    if (t == 0) gbase[nbuck] = E;
}

// ---------------- Phase A2: bin edges into bucket segments ----------------
__global__ __launch_bounds__(256) void k_bin(const int* __restrict__ src,
                                             const int* __restrict__ dst,
                                             int* __restrict__ gcur,
                                             int2* __restrict__ binned, int E, int per, int nbuck) {
    __shared__ int lh[512];
    __shared__ int lcur[512];
    for (int t = threadIdx.x; t < nbuck; t += 256) lh[t] = 0;
    __syncthreads();
    int lo = blockIdx.x * per, hi = min(E, lo + per);
    for (int e = lo + threadIdx.x; e < hi; e += 256)
        atomicAdd(&lh[dst[e] >> BSHIFT], 1);
    __syncthreads();
    for (int t = threadIdx.x; t < nbuck; t += 256) {
        int c = lh[t];
        lcur[t] = c ? atomicAdd(&gcur[t], c) : 0;
    }
    __syncthreads();
    for (int e = lo + threadIdx.x; e < hi; e += 256) {
        int d = dst[e];
        int b = d >> BSHIFT;
        int pos = atomicAdd(&lcur[b], 1);
        binned[pos] = make_int2(src[e], d);
    }
}

// ---------------- Phase B: per-bucket CSR build (single-writer regions) ----------------
__global__ __launch_bounds__(256) void k_bucket(const int2* __restrict__ binned,
                                                const int* __restrict__ gbase,
                                                float* __restrict__ dinv,
                                                int* __restrict__ rowstart,
                                                int2* __restrict__ csr, int N, int nbuck, int E) {
    __shared__ int hist[256];
    __shared__ float ldinv[256];
    __shared__ int lcur[256];
    __shared__ int ltmp[256];
    int b = blockIdx.x;
    int t = threadIdx.x;
    int nodeLo = b << BSHIFT;
    int nHere = min(256, N - nodeLo);
    int e0 = gbase[b], e1 = gbase[b + 1];
    hist[t] = 0;
    __syncthreads();
    for (int e = e0 + t; e < e1; e += 256)
        atomicAdd(&hist[binned[e].y - nodeLo], 1);
    __syncthreads();
    int deg = (t < nHere) ? hist[t] : 0;
    float di = (deg > 0) ? rsqrtf((float)deg) : 0.0f;
    if (t < nHere) { dinv[nodeLo + t] = di; }
    ldinv[t] = di;
    ltmp[t] = deg;
    __syncthreads();
    for (int off = 1; off < 256; off <<= 1) {
        int add = (t >= off) ? ltmp[t - off] : 0;
        __syncthreads();
        ltmp[t] += add;
        __syncthreads();
    }
    int lstart = ltmp[t] - deg;
    if (t < nHere) rowstart[nodeLo + t] = e0 + lstart;
    if (b == nbuck - 1 && t == 0) rowstart[N] = E;
    lcur[t] = lstart;
    __syncthreads();
    for (int e = e0 + t; e < e1; e += 256) {
        int2 sd = binned[e];
        int dl = sd.y - nodeLo;
        int pos = atomicAdd(&lcur[dl], 1);
        csr[e0 + pos] = make_int2(sd.x, __float_as_int(-ldinv[dl]));
    }
}

// ---------------- Phase C: apply dinv[src] ----------------
__global__ void k_weights(int2* __restrict__ csr, const float* __restrict__ dinv, int E) {
    int e = blockIdx.x * blockDim.x + threadIdx.x;
    if (e < E) {
        int2 c = csr[e];
        float w = __int_as_float(c.y) * dinv[c.x];
        csr[e] = make_int2(c.x, __float_as_int(w));
    }
}

// ---------------- fp32 -> fp16 cast ----------------
__global__ void k_cast(const float* __restrict__ x, __half* __restrict__ xh, int total) {
    int i = blockIdx.x * blockDim.x + threadIdx.x;
    if (i < total) xh[i] = __float2half(x[i]);
}

// ---------------- pack W[192][64] fp32 into B-fragment-ordered fp16 ----------------
// Wb[((tile*6+kk)*64+lane)*8+j] = W[kk*32+(lane>>4)*8+j][tile*16+(lane&15)]
__global__ void k_prepw(const float* __restrict__ W, _Float16* __restrict__ Wb) {
    int idx = blockIdx.x * 256 + threadIdx.x;   // 0..12287
    int j = idx & 7;
    int lane = (idx >> 3) & 63;
    int tk = idx >> 9;          // tile*6+kk
    int tile = tk / 6, kk = tk % 6;
    int k = kk * 32 + (lane >> 4) * 8 + j;
    int n = tile * 16 + (lane & 15);
    Wb[idx] = (_Float16)W[k * 64 + n];
}

// ---------------- propagation: y = prop(h)  (or 2*prop(h) - tx0) ----------------
__global__ __launch_bounds__(256) void k_prop(const __half* __restrict__ h,
                                              const int* __restrict__ rowstart,
                                              const int2* __restrict__ csr,
                                              const __half* __restrict__ tx0,
                                              __half* __restrict__ y, int N) {
    int gid = blockIdx.x * blockDim.x + threadIdx.x;
    int wave = gid >> 6;
    int lane = gid & 63;
    int node = wave * 2 + (lane >> 5);
    int c2 = lane & 31;
    if (node >= N) return;
    const __half2* h2 = (const __half2*)h;
    int e = rowstart[node];
    int e1 = rowstart[node + 1];
    float ax = 0.0f, ay = 0.0f;
    for (; e + 4 <= e1; e += 4) {
        int2 k0 = csr[e], k1 = csr[e + 1], k2 = csr[e + 2], k3 = csr[e + 3];
        __half2 g0 = h2[k0.x * 32 + c2];
        __half2 g1 = h2[k1.x * 32 + c2];
        __half2 g2 = h2[k2.x * 32 + c2];
        __half2 g3 = h2[k3.x * 32 + c2];
        float2 f0 = __half22float2(g0);
        float2 f1 = __half22float2(g1);
        float2 f2 = __half22float2(g2);
        float2 f3 = __half22float2(g3);
        float w0 = __int_as_float(k0.y), w1 = __int_as_float(k1.y);
        float w2 = __int_as_float(k2.y), w3 = __int_as_float(k3.y);
        ax = fmaf(w0, f0.x, ax); ay = fmaf(w0, f0.y, ay);
        ax = fmaf(w1, f1.x, ax); ay = fmaf(w1, f1.y, ay);
        ax = fmaf(w2, f2.x, ax); ay = fmaf(w2, f2.y, ay);
        ax = fmaf(w3, f3.x, ax); ay = fmaf(w3, f3.y, ay);
    }
    for (; e < e1; e++) {
        int2 k = csr[e];
        float2 f = __half22float2(h2[k.x * 32 + c2]);
        float w = __int_as_float(k.y);
        ax = fmaf(w, f.x, ax); ay = fmaf(w, f.y, ay);
    }
    if (tx0 != nullptr) {
        float2 t = __half22float2(((const __half2*)tx0)[node * 32 + c2]);
        ax = 2.0f * ax - t.x;
        ay = 2.0f * ay - t.y;
    }
    ((__half2*)y)[node * 32 + c2] = __floats2half2_rn(ax, ay);
}

// ---------------- MFMA dense combine + bias + ReLU + banked instance-norm stats ----------------
// One wave per 16 nodes; [16x192]@[192x64] via 6 K-steps x 4 N-tiles of
// mfma_f32_16x16x32_f16. A-frag: A[m=lane&15][k=q*8+j] -> 16B contiguous global
// load. B from pre-packed Wb (L1-hot). C/D: col=lane&15, row=q*4+reg.
template <typename TOUT>
__global__ __launch_bounds__(256) void k_dmm(const __half* __restrict__ tx0,
                                             const __half* __restrict__ tx1,
                                             const __half* __restrict__ tx2,
                                             const _Float16* __restrict__ Wb,
                                             const float* __restrict__ b,
                                             TOUT* __restrict__ out,
                                             float* __restrict__ statsP, int N) {
    __shared__ float sred[64];
    __shared__ float sq[64];
    int t = threadIdx.x;
    int w = t >> 6;
    int lane = t & 63;
    if (t < 64) { sred[t] = 0.f; sq[t] = 0.f; }
    __syncthreads();

    int nb16 = blockIdx.x * 64 + w * 16;
    int m = lane & 15, q = lane >> 4;
    int row = nb16 + m;
    int rowC = (row < N) ? row : 0;   // clamp OOB A-rows (results masked later)
    const __half* base0 = tx0 + (size_t)rowC * NCH;
    const __half* base1 = tx1 + (size_t)rowC * NCH;
    const __half* base2 = tx2 + (size_t)rowC * NCH;

    f32x4 acc[4];
#pragma unroll
    for (int tile = 0; tile < 4; tile++) acc[tile] = (f32x4){0.f, 0.f, 0.f, 0.f};

#pragma unroll
    for (int kk = 0; kk < 6; kk++) {
        const __half* ap = (kk < 2 ? base0 : (kk < 4 ? base1 : base2)) + (kk & 1) * 32 + q * 8;
        f16x8 a = *(const f16x8*)ap;
#pragma unroll
        for (int tile = 0; tile < 4; tile++) {
            f16x8 bf = *(const f16x8*)(Wb + ((size_t)(tile * 6 + kk) * 64 + lane) * 8);
            acc[tile] = __builtin_amdgcn_mfma_f32_16x16x32_f16(a, bf, acc[tile], 0, 0, 0);
        }
    }

#pragma unroll
    for (int tile = 0; tile < 4; tile++) {
        int ch = tile * 16 + m;
        float bb = b[ch];
        float s = 0.f, qq = 0.f;
#pragma unroll
        for (int r = 0; r < 4; r++) {
            int node = nb16 + q * 4 + r;
            float v = fmaxf(acc[tile][r] + bb, 0.f);
            if (node < N) {
                out[(size_t)node * NCH + ch] = (TOUT)v;
                s += v;
                qq = fmaf(v, v, qq);
            }
        }
        // reduce over the 4 q-groups holding this channel
        s += __shfl_xor(s, 16, 64);  s += __shfl_xor(s, 32, 64);
        qq += __shfl_xor(qq, 16, 64); qq += __shfl_xor(qq, 32, 64);
        if (q == 0) { atomicAdd(&sred[ch], s); atomicAdd(&sq[ch], qq); }
    }
    __syncthreads();
    if (t < 64) {
        int bank = blockIdx.x & (SBANKS - 1);
        atomicAdd(&statsP[bank * 128 + t], sred[t]);
        atomicAdd(&statsP[bank * 128 + 64 + t], sq[t]);
    }
}

__global__ void k_final(float* __restrict__ statsP, float invN) {
    int c = threadIdx.x;  // 64
    float S = 0.f, Q = 0.f;
    for (int k = 0; k < SBANKS; k++) {
        S += statsP[k * 128 + c];
        Q += statsP[k * 128 + 64 + c];
    }
    float m = S * invN;
    float var = Q * invN - m * m;
    statsP[SBANKS * 128 + c] = m;
    statsP[SBANKS * 128 + 64 + c] = rsqrtf(var + EPS);
}

__global__ void k_norm_h(__half* __restrict__ h, const float* __restrict__ statsP, int total) {
    int i = blockIdx.x * blockDim.x + threadIdx.x;
    if (i >= total) return;
    int lane = i & 63;
    h[i] = __float2half((__half2float(h[i]) - statsP[SBANKS * 128 + lane]) * statsP[SBANKS * 128 + 64 + lane]);
}

__global__ void k_norm_f(float* __restrict__ h, const float* __restrict__ statsP, int total) {
    int i = blockIdx.x * blockDim.x + threadIdx.x;
    if (i >= total) return;
    int lane = i & 63;
    h[i] = (h[i] - statsP[SBANKS * 128 + lane]) * statsP[SBANKS * 128 + 64 + lane];
}

// ---------------- launcher ----------------
extern "C" void kernel_launch(void* const* d_in, const int* in_sizes, int n_in,
                              void* d_out, int out_size, void* d_ws, size_t ws_size,
                              hipStream_t stream) {
    const float* x  = (const float*)d_in[0];
    const int*   ei = (const int*)d_in[1];
    const float* W1 = (const float*)d_in[2];
    const float* b1 = (const float*)d_in[3];
    const float* W2 = (const float*)d_in[4];
    const float* b2 = (const float*)d_in[5];
    float* out = (float*)d_out;

    const int N = in_sizes[0] / NCH;
    const int E = in_sizes[1] / 2;
    const int* src = ei;
    const int* dst = ei + E;
    const int nbuck = (N + 255) >> BSHIFT;

    // workspace carve (256B aligned)
    char* p = (char*)d_ws;
    auto alloc = [&](size_t bytes) {
        void* r = (void*)p;
        p += ((bytes + 255) / 256) * 256;
        return r;
    };
    float*  dinv     = (float*)alloc((size_t)N * 4);
    int*    rowstart = (int*)alloc((size_t)(N + 1) * 4);
    int*    cnt      = (int*)alloc((size_t)nbuck * 4);
    int*    gbase    = (int*)alloc((size_t)(nbuck + 1) * 4);
    int*    gcur     = (int*)alloc((size_t)nbuck * 4);
    int2*   csr      = (int2*)alloc((size_t)E * 8);
    __half* xh       = (__half*)alloc((size_t)N * NCH * 2);
    __half* Tx1      = (__half*)alloc((size_t)N * NCH * 2);
    __half* Tx2      = (__half*)alloc((size_t)N * NCH * 2);
    __half* A        = (__half*)alloc((size_t)N * NCH * 2);
    _Float16* Wb1    = (_Float16*)alloc(12288 * 2);
    _Float16* Wb2    = (_Float16*)alloc(12288 * 2);
    const int statsFloats = SBANKS * 128 + 128;
    float*  stats1   = (float*)alloc((size_t)statsFloats * 4);
    float*  stats2   = (float*)alloc((size_t)statsFloats * 4);

    // binned aliases Tx1 (dead before first k_prop writes Tx1)
    int2* binned = (int2*)Tx1;

    hipMemsetAsync(cnt, 0, (size_t)nbuck * 4, stream);
    hipMemsetAsync(stats1, 0, (size_t)statsFloats * 4, stream);
    hipMemsetAsync(stats2, 0, (size_t)statsFloats * 4, stream);

    const int TB = 256;
    const int per = (E + NBLKA - 1) / NBLKA;
    k_hist<<<NBLKA, TB, 0, stream>>>(dst, cnt, E, per, nbuck);
    k_bscan<<<1, 512, 0, stream>>>(cnt, gbase, gcur, nbuck, E);
    k_bin<<<NBLKA, TB, 0, stream>>>(src, dst, gcur, binned, E, per, nbuck);
    k_bucket<<<nbuck, TB, 0, stream>>>(binned, gbase, dinv, rowstart, csr, N, nbuck, E);
    k_weights<<<(E + TB - 1) / TB, TB, 0, stream>>>(csr, dinv, E);
    k_cast<<<(N * NCH + TB - 1) / TB, TB, 0, stream>>>(x, xh, N * NCH);
    k_prepw<<<48, TB, 0, stream>>>(W1, Wb1);
    k_prepw<<<48, TB, 0, stream>>>(W2, Wb2);

    const int propBlocks = ((N + 1) / 2 * 64 + TB - 1) / TB;
    const int dmmBlocks = (N + 63) / 64;
    const int normBlocks = (N * NCH + TB - 1) / TB;
    const float invN = 1.0f / (float)N;

    // ---- layer 1 ----
    k_prop<<<propBlocks, TB, 0, stream>>>(xh, rowstart, csr, nullptr, Tx1, N);
    k_prop<<<propBlocks, TB, 0, stream>>>(Tx1, rowstart, csr, xh, Tx2, N);
    k_dmm<__half><<<dmmBlocks, TB, 0, stream>>>(xh, Tx1, Tx2, Wb1, b1, A, stats1, N);
    k_final<<<1, 64, 0, stream>>>(stats1, invN);
    k_norm_h<<<normBlocks, TB, 0, stream>>>(A, stats1, N * NCH);

    // ---- layer 2 ----
    k_prop<<<propBlocks, TB, 0, stream>>>(A, rowstart, csr, nullptr, Tx1, N);
    k_prop<<<propBlocks, TB, 0, stream>>>(Tx1, rowstart, csr, A, Tx2, N);
    k_dmm<float><<<dmmBlocks, TB, 0, stream>>>(A, Tx1, Tx2, Wb2, b2, out, stats2, N);
    k_final<<<1, 64, 0, stream>>>(stats2, invN);
    k_norm_f<<<normBlocks, TB, 0, stream>>>(out, stats2, N * NCH);
}